// Round 3
// baseline (171.540 us; speedup 1.0000x reference)
//
#include <hip/hip_runtime.h>
#include <cstdint>
#include <cstddef>

// Problem constants (from reference setup_inputs)
#define BB 16
#define CC 7
#define HH 368
#define WW 640
#define LL (HH * WW)          // 235520 pixels per batch
#define NCLS 6                // classes 1..6 (background 0 skipped)
#define NCOMBO (BB * NCLS)    // 96
#define PXB 1024              // pixels per block (256 threads x 4 px)
#define BPB (LL / PXB)        // 230 blocks per batch
#define NBLK (BB * BPB)       // 3680 blocks total

// Order-preserving monoid over a contiguous pixel range (per class):
//   S   = sum of |d_i - d_prev| over consecutive masked pixels inside range
//   cnt = masked pixel count; first/last = d of first/last masked pixel
// Identity: cnt == 0. Combine adds the bridging |B.first - A.last|.
struct St { int S, cnt, first, last; };

__device__ inline St comb(const St& a, const St& b) {
    if (a.cnt == 0) return b;
    if (b.cnt == 0) return a;
    St r;
    r.S     = a.S + b.S + abs(b.first - a.last);
    r.cnt   = a.cnt + b.cnt;
    r.first = a.first;
    r.last  = b.last;
    return r;
}

// ---------------------------------------------------------------------------
// Kernel 1 (fused): soft-argmax -> floor -> per-class monoid scan, one pass.
// Thread t of block (b, bb) owns 4 contiguous pixels; loads 7 float4 (fully
// coalesced). seg never touches memory. Block-level interleaved-pairs LDS
// tree preserves pixel order. Output: blkStates[blk][cls] (int4).
// HBM floor: 105.5 MB read @ ~6.3 TB/s ≈ 17 us.
// ---------------------------------------------------------------------------
__global__ __launch_bounds__(256) void fused_kernel(const float* __restrict__ logits,
                                                    int4* __restrict__ blkStates) {
    int blk = blockIdx.x;
    int b  = blk / BPB;
    int bb = blk - b * BPB;
    int t  = threadIdx.x;
    int i  = bb * PXB + t * 4;            // pixel index within batch, 16B aligned
    const float* base = logits + (size_t)b * CC * LL + i;

    float x[CC][4];
#pragma unroll
    for (int c = 0; c < CC; ++c) {
        float4 v = *reinterpret_cast<const float4*>(base + (size_t)c * LL);
        x[c][0] = v.x; x[c][1] = v.y; x[c][2] = v.z; x[c][3] = v.w;
    }

    // 4 | 640 and i % 4 == 0 -> the 4-pixel group never crosses a row.
    int row = i / WW;
    int col = i - row * WW;
    int d0  = col - row;

    St st[NCLS];
#pragma unroll
    for (int c = 0; c < NCLS; ++c) { st[c].S = 0; st[c].cnt = 0; st[c].first = 0; st[c].last = 0; }

#pragma unroll
    for (int k = 0; k < 4; ++k) {
        float m = x[0][k];
#pragma unroll
        for (int c = 1; c < CC; ++c) m = fmaxf(m, x[c][k]);
        float s = 0.0f, w = 0.0f;
#pragma unroll
        for (int c = 0; c < CC; ++c) {
            float e = __expf(x[c][k] - m);
            s += e;
            w += e * (float)c;
        }
        // soft_argmax = (sum e_c * c) / (sum e_c); only its floor matters.
        int sv = (int)floorf(__fdividef(w, s));
        int d  = d0 + k;
#pragma unroll
        for (int c = 0; c < NCLS; ++c) {
            if (sv == c + 1) {
                if (st[c].cnt == 0) st[c].first = d;
                else                st[c].S += abs(d - st[c].last);
                st[c].last = d;
                st[c].cnt++;
            }
        }
    }

    __shared__ int4 red[NCLS][256];       // 24 KB
#pragma unroll
    for (int c = 0; c < NCLS; ++c)
        red[c][t] = make_int4(st[c].S, st[c].cnt, st[c].first, st[c].last);
    __syncthreads();

    // Interleaved-pairs tree: combines adjacent ranges only -> order-safe.
    for (int step = 1; step < 256; step <<= 1) {
        if ((t & (2 * step - 1)) == 0) {
#pragma unroll
            for (int c = 0; c < NCLS; ++c) {
                int4 A = red[c][t], B = red[c][t + step];
                St a{A.x, A.y, A.z, A.w}, bs{B.x, B.y, B.z, B.w};
                St r = comb(a, bs);
                red[c][t] = make_int4(r.S, r.cnt, r.first, r.last);
            }
        }
        __syncthreads();
    }

    if (t < NCLS) blkStates[(size_t)blk * NCLS + t] = red[t][0];
}

// ---------------------------------------------------------------------------
// Kernel 2 (combine + final): per (batch, class) combine the 230 per-block
// states in order, compute the combo's contribution, atomicAdd into out[0].
// out[0] is zeroed by a hipMemsetAsync graph node (harness re-poisons d_out
// to 0xAA before every replay). 96 fp32 atomic adds of ~0.04-magnitude
// values: ordering nondeterminism ~1e-6 << 0.078 threshold.
// ---------------------------------------------------------------------------
__global__ __launch_bounds__(256) void combine_kernel(const int4* __restrict__ blkStates,
                                                      float* __restrict__ out) {
    int combo = blockIdx.x;               // b * NCLS + (cls-1)
    int b = combo / NCLS;
    int c = combo - b * NCLS;
    int t = threadIdx.x;

    St st{0, 0, 0, 0};
    if (t < BPB) {
        int4 v = blkStates[(size_t)(b * BPB + t) * NCLS + c];
        st = St{v.x, v.y, v.z, v.w};
    }

    __shared__ int4 red[256];
    red[t] = make_int4(st.S, st.cnt, st.first, st.last);
    __syncthreads();

    for (int step = 1; step < 256; step <<= 1) {
        if ((t & (2 * step - 1)) == 0) {
            int4 A = red[t], B = red[t + step];
            St a{A.x, A.y, A.z, A.w}, bs{B.x, B.y, B.z, B.w};
            St r = comb(a, bs);
            red[t] = make_int4(r.S, r.cnt, r.first, r.last);
        }
        __syncthreads();
    }

    if (t == 0) {
        int n = red[0].y;
        if (n >= 2) {
            // npairs = n-1; mean = S / npairs; contribution = mean / (n+1)
            double res = ((double)red[0].x / (double)(n - 1)) / (double)(n + 1);
            atomicAdd(out, (float)res);
        }
    }
}

extern "C" void kernel_launch(void* const* d_in, const int* in_sizes, int n_in,
                              void* d_out, int out_size, void* d_ws, size_t ws_size,
                              hipStream_t stream) {
    const float* logits = (const float*)d_in[0];
    // d_in[1] (labels) is unused by the reference computation.
    float* out = (float*)d_out;

    int4* blkStates = (int4*)d_ws;        // 3680*6*16 = 353280 B

    // d_out is re-poisoned to 0xAA before every replay -> zero it (async,
    // graph-capturable memset node).
    hipMemsetAsync(out, 0, sizeof(float) * out_size, stream);
    fused_kernel<<<NBLK, 256, 0, stream>>>(logits, blkStates);
    combine_kernel<<<NCOMBO, 256, 0, stream>>>(blkStates, out);
}